// Round 3
// baseline (341.799 us; speedup 1.0000x reference)
//
#include <hip/hip_runtime.h>

// LengthRegulator: B=32, T=1024, D=384, T_OUT=4096
// out[b, p, :] = x[b, t(p), :] where t(p) = #{t : ends[t] <= p} (searchsorted
// right of inclusive-cumsum of max(dur,0)), valid for p < min(total, target).

#define BB 32
#define TT 1024
#define DD 384
#define TOUT 4096
#define D4 (DD / 4)   // 96 float4 per row

typedef float v4f __attribute__((ext_vector_type(4)));

// Kernel 1: one block per batch. int4 duration load + per-thread serial
// prefix + 256-wide LDS scan -> ends[1024] in LDS. Then a coalesced fill of
// idx[b, 0..4096): 16 interleaved branchless binary searches per thread.
// idx = frame (clipped) for valid rows, -1 for rows that must be zero.
__global__ __launch_bounds__(256) void lr_build_idx(
    const int4* __restrict__ dur4,      // [B, 256] (durations viewed as int4)
    const int* __restrict__ target_len, // [B]
    int* __restrict__ idx)              // [B, TOUT] (workspace)
{
    __shared__ int ends[TT];
    __shared__ int sums[256];
    __shared__ int s_limit;
    const int b = blockIdx.x;
    const int q = threadIdx.x;

    int4 d = dur4[b * 256 + q];
    const int d0 = d.x > 0 ? d.x : 0;
    const int d1 = d.y > 0 ? d.y : 0;
    const int d2 = d.z > 0 ? d.z : 0;
    const int d3 = d.w > 0 ? d.w : 0;
    const int e0 = d0, e1 = e0 + d1, e2 = e1 + d2, e3 = e2 + d3;
    sums[q] = e3;
    __syncthreads();

    // Hillis-Steele inclusive scan over 256 thread-sums (8 steps).
    #pragma unroll
    for (int off = 1; off < 256; off <<= 1) {
        int u = (q >= off) ? sums[q - off] : 0;
        __syncthreads();
        sums[q] += u;
        __syncthreads();
    }
    const int base = sums[q] - e3;  // exclusive prefix for this thread's 4
    ((int4*)ends)[q] = make_int4(base + e0, base + e1, base + e2, base + e3);

    if (q == 255) {
        const int total = base + e3;
        const int tl = target_len[b];
        s_limit = total < tl ? total : tl;
    }
    __syncthreads();

    const int lim = s_limit;
    // 16 positions per thread, strided by 256 for coalesced idx writes.
    int lo[16];
    #pragma unroll
    for (int k = 0; k < 16; ++k) lo[k] = 0;
    // Branchless binary search, steps interleaved across the 16 searches
    // so the 10 dependent LDS reads of each search overlap with the others.
    #pragma unroll
    for (int s = 512; s > 0; s >>= 1) {
        #pragma unroll
        for (int k = 0; k < 16; ++k) {
            const int p = q + 256 * k;
            lo[k] += (ends[lo[k] + s - 1] <= p) ? s : 0;
        }
    }
    #pragma unroll
    for (int k = 0; k < 16; ++k) {
        const int p = q + 256 * k;
        int t = lo[k] > TT - 1 ? TT - 1 : lo[k];
        idx[b * TOUT + p] = (p < lim) ? t : -1;
    }
}

// Kernel 2: one thread per 4 consecutive float4 (64 B). 24 threads per output
// row. Non-temporal stores (out is never re-read; keep L2 for x).
__global__ __launch_bounds__(256) void lr_gather(
    const v4f* __restrict__ x,        // [B, T, D4]
    const int* __restrict__ idx,      // [B, TOUT]
    v4f* __restrict__ out)            // [B, TOUT, D4]
{
    const int b = blockIdx.y;
    const int r = blockIdx.x * 256 + threadIdx.x;  // [0, TOUT*24)
    const int p = r / 24;
    const int c4 = (r - p * 24) << 2;              // float4 col: 0,4,...,92

    const int t = idx[b * TOUT + p];
    v4f v0 = (v4f)(0.f);
    v4f v1 = v0, v2 = v0, v3 = v0;
    if (t >= 0) {
        const v4f* __restrict__ row = x + (b * TT + t) * D4 + c4;
        v0 = row[0];
        v1 = row[1];
        v2 = row[2];
        v3 = row[3];
    }
    v4f* o = out + (b * TOUT + p) * D4 + c4;
    __builtin_nontemporal_store(v0, o + 0);
    __builtin_nontemporal_store(v1, o + 1);
    __builtin_nontemporal_store(v2, o + 2);
    __builtin_nontemporal_store(v3, o + 3);
}

extern "C" void kernel_launch(void* const* d_in, const int* in_sizes, int n_in,
                              void* d_out, int out_size, void* d_ws, size_t ws_size,
                              hipStream_t stream) {
    const float* x        = (const float*)d_in[0];
    const int* durations  = (const int*)d_in[1];
    const int* target_len = (const int*)d_in[2];
    float* out            = (float*)d_out;

    int* idx = (int*)d_ws;  // B*TOUT ints = 512 KB

    lr_build_idx<<<BB, 256, 0, stream>>>((const int4*)durations, target_len, idx);

    dim3 grid((TOUT * 24) / 256, BB);  // 384 x 32 blocks
    lr_gather<<<grid, 256, 0, stream>>>((const v4f*)x, idx, (v4f*)out);
}

// Round 4
// 245.475 us; speedup vs baseline: 1.3924x; 1.3924x over previous
//
#include <hip/hip_runtime.h>

// LengthRegulator: B=32, T=1024, D=384, T_OUT=4096
// out[b, p, :] = x[b, t(p), :] where t(p) = #{t : ends[t] <= p} (searchsorted
// right of inclusive-cumsum of max(dur,0)), valid for p < min(total, target).

#define BB 32
#define TT 1024
#define DD 384
#define TOUT 4096
#define D4 (DD / 4)          // 96 float4 per row
#define N4 (TOUT * D4)       // 393216 float4 per batch

typedef float v4f __attribute__((ext_vector_type(4)));

// Kernel 1: one block per batch. int4 duration load + per-thread serial
// prefix + 256-wide LDS scan -> ends[1024] in LDS. Then a coalesced fill of
// idx[b, 0..4096): 16 interleaved branchless binary searches per thread.
// idx = frame (clipped) for valid rows, -1 for rows that must be zero.
__global__ __launch_bounds__(256) void lr_build_idx(
    const int4* __restrict__ dur4,      // [B, 256] (durations viewed as int4)
    const int* __restrict__ target_len, // [B]
    int* __restrict__ idx)              // [B, TOUT] (workspace)
{
    __shared__ int ends[TT];
    __shared__ int sums[256];
    __shared__ int s_limit;
    const int b = blockIdx.x;
    const int q = threadIdx.x;

    int4 d = dur4[b * 256 + q];
    const int d0 = d.x > 0 ? d.x : 0;
    const int d1 = d.y > 0 ? d.y : 0;
    const int d2 = d.z > 0 ? d.z : 0;
    const int d3 = d.w > 0 ? d.w : 0;
    const int e0 = d0, e1 = e0 + d1, e2 = e1 + d2, e3 = e2 + d3;
    sums[q] = e3;
    __syncthreads();

    // Hillis-Steele inclusive scan over 256 thread-sums (8 steps).
    #pragma unroll
    for (int off = 1; off < 256; off <<= 1) {
        int u = (q >= off) ? sums[q - off] : 0;
        __syncthreads();
        sums[q] += u;
        __syncthreads();
    }
    const int base = sums[q] - e3;  // exclusive prefix for this thread's 4
    ((int4*)ends)[q] = make_int4(base + e0, base + e1, base + e2, base + e3);

    if (q == 255) {
        const int total = base + e3;
        const int tl = target_len[b];
        s_limit = total < tl ? total : tl;
    }
    __syncthreads();

    const int lim = s_limit;
    // 16 positions per thread, strided by 256 for coalesced idx writes.
    int lo[16];
    #pragma unroll
    for (int k = 0; k < 16; ++k) lo[k] = 0;
    // Branchless binary search, steps interleaved across the 16 searches
    // so the 10 dependent LDS reads of each search overlap with the others.
    #pragma unroll
    for (int s = 512; s > 0; s >>= 1) {
        #pragma unroll
        for (int k = 0; k < 16; ++k) {
            const int p = q + 256 * k;
            lo[k] += (ends[lo[k] + s - 1] <= p) ? s : 0;
        }
    }
    #pragma unroll
    for (int k = 0; k < 16; ++k) {
        const int p = q + 256 * k;
        int t = lo[k] > TT - 1 ? TT - 1 : lo[k];
        idx[b * TOUT + p] = (p < lim) ? t : -1;
    }
}

// Kernel 2: 4 float4 per thread, strided by 256 so every store instruction
// writes 64 consecutive float4 per wave (4 KB contiguous -> full HBM lines,
// safe for non-temporal). idx loads are wave-broadcast L1 hits; x reads are
// row-coalesced and L2/L3-resident.
__global__ __launch_bounds__(256) void lr_gather(
    const v4f* __restrict__ x,        // [B, T, D4]
    const int* __restrict__ idx,      // [B, TOUT]
    v4f* __restrict__ out)            // [B, TOUT, D4]
{
    const int b = blockIdx.y;
    const int base = blockIdx.x * 1024 + threadIdx.x;  // float4 index in batch
    const int* __restrict__ idx_b = idx + b * TOUT;
    const v4f* __restrict__ x_b = x + b * TT * D4;
    v4f* __restrict__ out_b = out + b * N4;

    #pragma unroll
    for (int k = 0; k < 4; ++k) {
        const int i = base + k * 256;
        const int p = i / D4;           // magic-mul division
        const int c = i - p * D4;
        const int t = idx_b[p];
        v4f v = (v4f)(0.f);
        if (t >= 0) v = x_b[t * D4 + c];
        __builtin_nontemporal_store(v, out_b + i);
    }
}

extern "C" void kernel_launch(void* const* d_in, const int* in_sizes, int n_in,
                              void* d_out, int out_size, void* d_ws, size_t ws_size,
                              hipStream_t stream) {
    const float* x        = (const float*)d_in[0];
    const int* durations  = (const int*)d_in[1];
    const int* target_len = (const int*)d_in[2];
    float* out            = (float*)d_out;

    int* idx = (int*)d_ws;  // B*TOUT ints = 512 KB

    lr_build_idx<<<BB, 256, 0, stream>>>((const int4*)durations, target_len, idx);

    dim3 grid(N4 / 1024, BB);  // 384 x 32 blocks
    lr_gather<<<grid, 256, 0, stream>>>((const v4f*)x, idx, (v4f*)out);
}